// Round 3
// baseline (421.944 us; speedup 1.0000x reference)
//
#include <hip/hip_runtime.h>
#include <hip/hip_bf16.h>
#include <cstdint>
#include <cstddef>

// Problem constants
#define BATCH 512
#define NUSER 32
#define NM    64
#define FEATB 62
// rows through MLP = BATCH*NUSER = 16384, input width = 2 + 62 = 64

typedef short bf16x8 __attribute__((ext_vector_type(8)));   // 8 bf16 (4 VGPRs) — MFMA A/B frag
typedef float f32x4  __attribute__((ext_vector_type(4)));   // MFMA C/D frag
typedef float f32x4v __attribute__((ext_vector_type(4)));   // ext-vector float4 (nontemporal-load eligible)

__device__ __forceinline__ float bf2f(short s) {
    union { unsigned int u; float f; } v;
    v.u = ((unsigned int)(unsigned short)s) << 16;
    return v.f;
}

// ---------------------------------------------------------------------------
// Kernel 1: ALL weight transposes in one launch.  W[K][N] f32 -> WT[N][K] bf16
// so MFMA B-fragments are contiguous-in-K 16B loads. 144 blocks, L2-resident.
// ---------------------------------------------------------------------------
__global__ void transpose_cvt_all_kernel(
        const float* __restrict__ W1, const float* __restrict__ W2,
        const float* __restrict__ W3, const float* __restrict__ W4,
        __hip_bfloat16* __restrict__ WT1, __hip_bfloat16* __restrict__ WT2,
        __hip_bfloat16* __restrict__ WT3, __hip_bfloat16* __restrict__ WT4) {
    __shared__ float t[64][65];          // +1 pad: conflict-free transposed reads
    const int idx = blockIdx.x;
    const float* W; __hip_bfloat16* WT; int K, N, kt, nt;
    if (idx < 8)        { W = W1; WT = WT1; K = 64;  N = 512; kt = 0;             nt = idx;          }
    else if (idx < 72)  { W = W2; WT = WT2; K = 512; N = 512; kt = (idx-8) >> 3;  nt = (idx-8) & 7;  }
    else if (idx < 136) { W = W3; WT = WT3; K = 512; N = 512; kt = (idx-72) >> 3; nt = (idx-72) & 7; }
    else                { W = W4; WT = WT4; K = 512; N = 2;   kt = idx - 136;     nt = 0;            }
    const int k0 = kt * 64, n0 = nt * 64;
    #pragma unroll
    for (int i = 0; i < 16; ++i) {
        int lin = threadIdx.x + i * 256;
        int r = lin >> 6, c = lin & 63;  // r: k-offset, c: n-offset (coalesced read)
        if (k0 + r < K && n0 + c < N) t[r][c] = W[(size_t)(k0 + r) * N + (n0 + c)];
    }
    __syncthreads();
    #pragma unroll
    for (int i = 0; i < 16; ++i) {
        int lin = threadIdx.x + i * 256;
        int r = lin >> 6, c = lin & 63;  // r: n-offset, c: k-offset (coalesced write)
        if (n0 + r < N && k0 + c < K)
            WT[(size_t)(n0 + r) * K + (k0 + c)] = __float2bfloat16(t[c][r]);
    }
}

// ---------------------------------------------------------------------------
// LDS helpers: X tile [32 rows][64 bf16 cols], 128 B rows, XOR-swizzled
// (G4: ^((row&7)<<4) balances all 32 banks for the MFMA A-reads).
// ---------------------------------------------------------------------------
__device__ __forceinline__ void xs_store_pair(char* xs, int row, int col, float a, float b) {
    __hip_bfloat162 h;
    h.x = __float2bfloat16(a); h.y = __float2bfloat16(b);
    *reinterpret_cast<__hip_bfloat162*>(
        xs + (((unsigned)row * 128u + (unsigned)col * 2u) ^ ((unsigned)(row & 7) << 4))) = h;
}
// j indexes a float4 within the batch's [32][62] B_norm grid (feat = 4j%62 is even)
__device__ __forceinline__ void xs_store4(char* xs, int j, float s0, float s1, float s2, float s3) {
    const int e = 4 * j;
    const int user = e / FEATB, feat = e % FEATB;
    xs_store_pair(xs, user, 2 + feat, s0, s1);
    if (feat == 60) xs_store_pair(xs, user + 1, 2, s2, s3);   // crosses user boundary
    else            xs_store_pair(xs, user, 4 + feat, s2, s3);
}

// ---------------------------------------------------------------------------
// One MLP layer: A (32 x K) from swizzled LDS, W^T (512 x K) bf16 from L2,
// 16x16x32 bf16 MFMA, bias+ReLU epilogue back to swizzled LDS.
// Wave w owns cols [w*128, w*128+128).
// A/B fragments both use the contiguous-8-in-K per-lane convention, so any
// k-slot permutation inside the HW layout cancels in the dot product.
// ---------------------------------------------------------------------------
template<int K, int ASTRIDE>
__device__ __forceinline__ void mlp_layer(const char* a_lds,
                                          const __hip_bfloat16* __restrict__ wt,  // [512][K]
                                          const float* __restrict__ bias,
                                          char* out_lds,                          // [32][512] bf16, swizzled
                                          int wave, int lane) {
    f32x4 acc[2][8] = {};
    const int colbase = wave * 128;
    const int lrow = lane & 15;
    const int kg   = (lane >> 4) * 8;
    const unsigned int sw = (unsigned int)(lrow & 7) << 4;  // (16+lrow)&7 == lrow&7

    #pragma unroll 2
    for (int ks = 0; ks < K / 32; ++ks) {
        const int k0 = ks * 32 + kg;
        bf16x8 a0 = *reinterpret_cast<const bf16x8*>(a_lds + ((((unsigned)lrow        * ASTRIDE + k0 * 2)) ^ sw));
        bf16x8 a1 = *reinterpret_cast<const bf16x8*>(a_lds + ((((unsigned)(16 + lrow) * ASTRIDE + k0 * 2)) ^ sw));
        bf16x8 bfrag[8];
        #pragma unroll
        for (int n = 0; n < 8; ++n) {
            const int col = colbase + n * 16 + lrow;
            bfrag[n] = *reinterpret_cast<const bf16x8*>(wt + (size_t)col * K + k0);
        }
        #pragma unroll
        for (int n = 0; n < 8; ++n) {
            acc[0][n] = __builtin_amdgcn_mfma_f32_16x16x32_bf16(a0, bfrag[n], acc[0][n], 0, 0, 0);
            acc[1][n] = __builtin_amdgcn_mfma_f32_16x16x32_bf16(a1, bfrag[n], acc[1][n], 0, 0, 0);
        }
    }

    // epilogue: +bias, ReLU, bf16, swizzled LDS store
    // C/D layout (m89-verified): col = lane&15, row = (lane>>4)*4 + reg
    const int rg = (lane >> 4) * 4;
    #pragma unroll
    for (int m = 0; m < 2; ++m) {
        #pragma unroll
        for (int n = 0; n < 8; ++n) {
            const int col = colbase + n * 16 + lrow;
            const float bv = bias[col];
            #pragma unroll
            for (int r = 0; r < 4; ++r) {
                const int row = m * 16 + rg + r;
                float v = acc[m][n][r] + bv;
                v = fmaxf(v, 0.f);
                *reinterpret_cast<__hip_bfloat16*>(
                    out_lds + (((unsigned)row * 1024u + (unsigned)col * 2u) ^ ((unsigned)(row & 7) << 4)))
                    = __float2bfloat16(v);
            }
        }
    }
}

// ---------------------------------------------------------------------------
// Kernel 2 (mega): per-batch  B-reduce -> concat -> 4-layer MLP -> sigmoid
// -> per-batch normalize. One block = one batch (32 users). 4 waves.
// LDS ~68 KB -> 2 blocks/CU, 8 waves/CU. Phase 0 streams this batch's 508 KB
// B-slice (nontemporal: read-once, keep WT panels L2-resident).
// ---------------------------------------------------------------------------
__global__ __launch_bounds__(256, 2) void fused_kernel(
    const float* __restrict__ B, const float* __restrict__ D,
    const __hip_bfloat16* __restrict__ WT1, const float* __restrict__ b1,
    const __hip_bfloat16* __restrict__ WT2, const float* __restrict__ b2,
    const __hip_bfloat16* __restrict__ WT3, const float* __restrict__ b3,
    const __hip_bfloat16* __restrict__ WT4, const float* __restrict__ b4,
    const float* __restrict__ Pp, float* __restrict__ out) {

    __shared__ __align__(16) char xs[NUSER * 64 * 2];        // 4 KB  (X tile)
    __shared__ __align__(16) char act0[NUSER * 512 * 2];     // 32 KB
    __shared__ __align__(16) char act1[NUSER * 512 * 2];     // 32 KB
    __shared__ float d1s[NUSER][2];
    __shared__ float colsum[2];

    const int batch = blockIdx.x;
    const int tid = threadIdx.x;
    const int wave = tid >> 6, lane = tid & 63;

    // ---- Phase 0: B_norm = sum_m B[batch,m,:,:]  (508 KB stream) + concat D.
    // 496 float4 jobs cover 32*62 floats. Thread t owns job t and (if <496)
    // job t+256. ONE uniform m-loop; the second load is exec-mask predicated
    // (no loop duplication -> no wave-3 double-loop straggler). Each wave
    // reads 1 KB contiguous per m-step (coalesced).
    {
        const f32x4v* p = reinterpret_cast<const f32x4v*>(B + (size_t)batch * (NM * NUSER * FEATB));
        const int j0 = tid, j1 = tid + 256;
        const bool hasj1 = (j1 < 496);
        f32x4v s0 = {0.f, 0.f, 0.f, 0.f};
        f32x4v s1 = {0.f, 0.f, 0.f, 0.f};
        #pragma unroll 4
        for (int m = 0; m < NM; ++m) {
            s0 += __builtin_nontemporal_load(p + (size_t)j0 + (size_t)m * 496);
            if (hasj1)
                s1 += __builtin_nontemporal_load(p + (size_t)j1 + (size_t)m * 496);
        }
        xs_store4(xs, j0, s0.x, s0.y, s0.z, s0.w);
        if (hasj1) {
            xs_store4(xs, j1, s1.x, s1.y, s1.z, s1.w);
        } else {
            const int dj = tid - 240;             // 16 jobs x float4 = 64 floats of D
            float4 v = reinterpret_cast<const float4*>(D + (size_t)batch * NUSER * 2)[dj];
            xs_store_pair(xs, 2 * dj,     0, v.x, v.y);
            xs_store_pair(xs, 2 * dj + 1, 0, v.z, v.w);
        }
    }
    __syncthreads();

    // ---- Phases 1-3: MFMA layers
    mlp_layer<64, 128>(xs, WT1, b1, act0, wave, lane);
    __syncthreads();
    mlp_layer<512, 1024>(act0, WT2, b2, act1, wave, lane);
    __syncthreads();
    mlp_layer<512, 1024>(act1, WT3, b3, act0, wave, lane);
    __syncthreads();

    // ---- Layer 4 (N=2, K=512) on VALU + sigmoid. 4 threads per output elem.
    {
        const int row = tid >> 3, col = (tid >> 2) & 1, part = tid & 3;
        float s = 0.f;
        #pragma unroll
        for (int kk = 0; kk < 128; kk += 8) {
            const int k = part * 128 + kk;
            bf16x8 av = *reinterpret_cast<const bf16x8*>(
                act0 + (((unsigned)row * 1024u + (unsigned)k * 2u) ^ ((unsigned)(row & 7) << 4)));
            bf16x8 wv = *reinterpret_cast<const bf16x8*>(WT4 + col * 512 + k);
            #pragma unroll
            for (int jj = 0; jj < 8; ++jj) s += bf2f(av[jj]) * bf2f(wv[jj]);
        }
        s += __shfl_xor(s, 1, 64);
        s += __shfl_xor(s, 2, 64);
        if (part == 0) {
            const float z = s + b4[col];
            d1s[row][col] = 1.f / (1.f + expf(-z));
        }
    }
    __syncthreads();

    // ---- per-batch normalization over the 32 users
    if (tid < 2) {
        float s = 0.f;
        #pragma unroll
        for (int r = 0; r < NUSER; ++r) s += d1s[r][tid];
        colsum[tid] = s;
    }
    __syncthreads();
    if (tid < 64) {
        out[(size_t)batch * 64 + tid] = Pp[0] * d1s[tid >> 1][tid & 1] / colsum[tid & 1];
    }
}

// ---------------------------------------------------------------------------
// Launch. d_in order: D, B, P_pow_normalized, D_0(unused), W1,b1, W2,b2, W3,b3, W4,b4
// ws layout: WT1(64 KB) | WT2(512 KB) | WT3(512 KB) | WT4(2 KB)  ~1.06 MB
// ---------------------------------------------------------------------------
extern "C" void kernel_launch(void* const* d_in, const int* in_sizes, int n_in,
                              void* d_out, int out_size, void* d_ws, size_t ws_size,
                              hipStream_t stream) {
    const float* D  = (const float*)d_in[0];
    const float* B  = (const float*)d_in[1];
    const float* Pp = (const float*)d_in[2];
    const float* W1 = (const float*)d_in[4];
    const float* b1 = (const float*)d_in[5];
    const float* W2 = (const float*)d_in[6];
    const float* b2 = (const float*)d_in[7];
    const float* W3 = (const float*)d_in[8];
    const float* b3 = (const float*)d_in[9];
    const float* W4 = (const float*)d_in[10];
    const float* b4 = (const float*)d_in[11];
    float* out = (float*)d_out;

    char* ws = (char*)d_ws;
    __hip_bfloat16* WT1 = (__hip_bfloat16*)(ws);
    __hip_bfloat16* WT2 = (__hip_bfloat16*)(ws + 65536);
    __hip_bfloat16* WT3 = (__hip_bfloat16*)(ws + 65536 + 524288);
    __hip_bfloat16* WT4 = (__hip_bfloat16*)(ws + 65536 + 524288 + 524288);

    transpose_cvt_all_kernel<<<144, 256, 0, stream>>>(W1, W2, W3, W4, WT1, WT2, WT3, WT4);

    fused_kernel<<<BATCH, 256, 0, stream>>>(B, D, WT1, b1, WT2, b2, WT3, b3,
                                            WT4, b4, Pp, out);
}

// Round 7
// 397.374 us; speedup vs baseline: 1.0618x; 1.0618x over previous
//
#include <hip/hip_runtime.h>
#include <hip/hip_bf16.h>
#include <cstdint>
#include <cstddef>

// Problem constants
#define BATCH 512
#define NUSER 32
#define NM    64
#define FEATB 62
// rows through MLP = BATCH*NUSER = 16384, input width = 2 + 62 = 64
// This version: one block = TWO batches (M=64 rows), 512 threads, 256 blocks.
// Halves per-batch weight re-reads from L2 vs the M=32 version.

#define SLICE_F4 (NM * NUSER * FEATB / 4)   // 31744 float4 per batch slice

typedef short bf16x8 __attribute__((ext_vector_type(8)));   // 8 bf16 (4 VGPRs) — MFMA A/B frag
typedef float f32x4  __attribute__((ext_vector_type(4)));   // MFMA C/D frag
typedef float f32x4v __attribute__((ext_vector_type(4)));   // ext-vector float4 (nontemporal-load eligible)

__device__ __forceinline__ float bf2f(short s) {
    union { unsigned int u; float f; } v;
    v.u = ((unsigned int)(unsigned short)s) << 16;
    return v.f;
}

// ---------------------------------------------------------------------------
// Kernel 1: ALL weight transposes in one launch.  W[K][N] f32 -> WT[N][K] bf16
// so MFMA B-fragments are contiguous-in-K 16B loads. 144 blocks, L2-resident.
// ---------------------------------------------------------------------------
__global__ void transpose_cvt_all_kernel(
        const float* __restrict__ W1, const float* __restrict__ W2,
        const float* __restrict__ W3, const float* __restrict__ W4,
        __hip_bfloat16* __restrict__ WT1, __hip_bfloat16* __restrict__ WT2,
        __hip_bfloat16* __restrict__ WT3, __hip_bfloat16* __restrict__ WT4) {
    __shared__ float t[64][65];          // +1 pad: conflict-free transposed reads
    const int idx = blockIdx.x;
    const float* W; __hip_bfloat16* WT; int K, N, kt, nt;
    if (idx < 8)        { W = W1; WT = WT1; K = 64;  N = 512; kt = 0;             nt = idx;          }
    else if (idx < 72)  { W = W2; WT = WT2; K = 512; N = 512; kt = (idx-8) >> 3;  nt = (idx-8) & 7;  }
    else if (idx < 136) { W = W3; WT = WT3; K = 512; N = 512; kt = (idx-72) >> 3; nt = (idx-72) & 7; }
    else                { W = W4; WT = WT4; K = 512; N = 2;   kt = idx - 136;     nt = 0;            }
    const int k0 = kt * 64, n0 = nt * 64;
    #pragma unroll
    for (int i = 0; i < 16; ++i) {
        int lin = threadIdx.x + i * 256;
        int r = lin >> 6, c = lin & 63;  // r: k-offset, c: n-offset (coalesced read)
        if (k0 + r < K && n0 + c < N) t[r][c] = W[(size_t)(k0 + r) * N + (n0 + c)];
    }
    __syncthreads();
    #pragma unroll
    for (int i = 0; i < 16; ++i) {
        int lin = threadIdx.x + i * 256;
        int r = lin >> 6, c = lin & 63;  // r: n-offset, c: k-offset (coalesced write)
        if (n0 + r < N && k0 + c < K)
            WT[(size_t)(n0 + r) * K + (k0 + c)] = __float2bfloat16(t[c][r]);
    }
}

// ---------------------------------------------------------------------------
// LDS helpers: X tile [64 rows][64 bf16 cols], 128 B rows, XOR-swizzled
// (G4: ^((row&7)<<4) balances all 32 banks for the MFMA A-reads).
// ---------------------------------------------------------------------------
__device__ __forceinline__ void xs_store_pair(char* xs, int row, int col, float a, float b) {
    __hip_bfloat162 h;
    h.x = __float2bfloat16(a); h.y = __float2bfloat16(b);
    *reinterpret_cast<__hip_bfloat162*>(
        xs + (((unsigned)row * 128u + (unsigned)col * 2u) ^ ((unsigned)(row & 7) << 4))) = h;
}
// jj indexes a float4 within one batch's [32][62] B_norm grid; rowbase = 0 or 32.
__device__ __forceinline__ void xs_store4(char* xs, int rowbase, int jj,
                                          float s0, float s1, float s2, float s3) {
    const int e = 4 * jj;
    const int user = rowbase + e / FEATB, feat = e % FEATB;   // feat is even
    xs_store_pair(xs, user, 2 + feat, s0, s1);
    if (feat == 60) xs_store_pair(xs, user + 1, 2, s2, s3);   // crosses user boundary
    else            xs_store_pair(xs, user, 4 + feat, s2, s3);
}

// ---------------------------------------------------------------------------
// One MLP layer: A (64 x K) from swizzled LDS, W^T (512 x K) bf16 from L2,
// 16x16x32 bf16 MFMA (validated absmax 3.7e-4), bias+ReLU epilogue to LDS.
// 8 waves; wave w owns cols [w*64, w*64+64). INPLACE: out_lds == a_lds is
// safe via the mid-barrier (all reads of a_lds complete before any store).
// ---------------------------------------------------------------------------
template<int K, int ASTRIDE, bool INPLACE>
__device__ __forceinline__ void mlp_layer(const char* a_lds,
                                          const __hip_bfloat16* __restrict__ wt,  // [512][K]
                                          const float* __restrict__ bias,
                                          char* out_lds,                          // [64][512] bf16, swizzled
                                          int wave, int lane) {
    f32x4 acc[4][4] = {};
    const int colbase = wave * 64;
    const int lrow = lane & 15;
    const int kg   = (lane >> 4) * 8;
    const unsigned int sw = (unsigned int)(lrow & 7) << 4;  // (16m+lrow)&7 == lrow&7

    #pragma unroll 2
    for (int ks = 0; ks < K / 32; ++ks) {
        const int k0 = ks * 32 + kg;
        bf16x8 a[4];
        #pragma unroll
        for (int m = 0; m < 4; ++m)
            a[m] = *reinterpret_cast<const bf16x8*>(
                a_lds + ((((unsigned)(m * 16 + lrow) * ASTRIDE + k0 * 2)) ^ sw));
        bf16x8 bfrag[4];
        #pragma unroll
        for (int n = 0; n < 4; ++n) {
            const int col = colbase + n * 16 + lrow;
            bfrag[n] = *reinterpret_cast<const bf16x8*>(wt + (size_t)col * K + k0);
        }
        #pragma unroll
        for (int n = 0; n < 4; ++n)
            #pragma unroll
            for (int m = 0; m < 4; ++m)
                acc[m][n] = __builtin_amdgcn_mfma_f32_16x16x32_bf16(a[m], bfrag[n], acc[m][n], 0, 0, 0);
    }

    if (INPLACE) __syncthreads();   // drain ALL waves' reads before overwriting

    // epilogue: +bias, ReLU, bf16, swizzled LDS store
    // C/D layout (m89-verified): col = lane&15, row = (lane>>4)*4 + reg
    const int rg = (lane >> 4) * 4;
    #pragma unroll
    for (int m = 0; m < 4; ++m) {
        #pragma unroll
        for (int n = 0; n < 4; ++n) {
            const int col = colbase + n * 16 + lrow;
            const float bv = bias[col];
            #pragma unroll
            for (int r = 0; r < 4; ++r) {
                const int row = m * 16 + rg + r;
                float v = acc[m][n][r] + bv;
                v = fmaxf(v, 0.f);
                *reinterpret_cast<__hip_bfloat16*>(
                    out_lds + (((unsigned)row * 1024u + (unsigned)col * 2u) ^ ((unsigned)(row & 7) << 4)))
                    = __float2bfloat16(v);
            }
        }
    }
}

// ---------------------------------------------------------------------------
// Kernel 2 (mega): per block: TWO batches. B-reduce -> concat -> 4-layer MLP
// -> sigmoid -> per-batch normalize. 512 threads (8 waves), 256 blocks.
// LDS ~74 KB; single in-place act buffer. Per-CU L2 weight traffic halves
// vs M=32 (1.05 MB serves 2 batches).
// ---------------------------------------------------------------------------
__global__ __launch_bounds__(512, 2) void fused_kernel(
    const float* __restrict__ B, const float* __restrict__ D,
    const __hip_bfloat16* __restrict__ WT1, const float* __restrict__ b1,
    const __hip_bfloat16* __restrict__ WT2, const float* __restrict__ b2,
    const __hip_bfloat16* __restrict__ WT3, const float* __restrict__ b3,
    const __hip_bfloat16* __restrict__ WT4, const float* __restrict__ b4,
    const float* __restrict__ Pp, float* __restrict__ out) {

    __shared__ __align__(16) char xs[64 * 64 * 2];           // 8 KB  (X tile, 2 batches)
    __shared__ __align__(16) char act[64 * 512 * 2];         // 64 KB (in-place act)
    __shared__ float d1s[64][2];
    __shared__ float colsum[2][2];

    const int b0 = blockIdx.x * 2;       // this block's two batches: b0, b0+1
    const int tid = threadIdx.x;
    const int wave = tid >> 6, lane = tid & 63;

    // ---- Phase 0: B_norm = sum_m B[b,m,:,:] for b0 and b0+1 (1.02 MB stream)
    // Job space (float4): [0,496) b0-B | [496,992) b1-B | 16 D-b0 | 16 D-b1.
    // Thread t owns jobs t and t+512. Uniform m-loop, 2 nontemporal streams.
    {
        const f32x4v* p = reinterpret_cast<const f32x4v*>(B) + (size_t)b0 * SLICE_F4;
        const bool s0_b1 = (tid >= 496);                  // stream0: which batch
        const int  jj0   = s0_b1 ? tid - 496 : tid;
        const bool has1  = (tid < 480);                   // stream1 is a B-job
        const int  jj1   = tid + 16;                      // (only valid if has1)
        const f32x4v* p0 = p + (s0_b1 ? SLICE_F4 : 0) + jj0;
        const f32x4v* p1 = p + SLICE_F4 + jj1;
        f32x4v s0 = {0.f, 0.f, 0.f, 0.f};
        f32x4v s1 = {0.f, 0.f, 0.f, 0.f};
        #pragma unroll 8
        for (int m = 0; m < NM; ++m) {
            s0 += __builtin_nontemporal_load(p0 + (size_t)m * 496);
            if (has1)
                s1 += __builtin_nontemporal_load(p1 + (size_t)m * 496);
        }
        xs_store4(xs, s0_b1 ? 32 : 0, jj0, s0.x, s0.y, s0.z, s0.w);
        if (has1) {
            xs_store4(xs, 32, jj1, s1.x, s1.y, s1.z, s1.w);
        } else {
            // 32 threads handle the D concat: 16 float4 per batch (64 floats)
            const bool db1 = (tid >= 496);
            const int  dj  = db1 ? tid - 496 : tid - 480;
            const int  rb  = db1 ? 32 : 0;
            float4 v = reinterpret_cast<const float4*>(
                           D + (size_t)(b0 + (db1 ? 1 : 0)) * NUSER * 2)[dj];
            xs_store_pair(xs, rb + 2 * dj,     0, v.x, v.y);
            xs_store_pair(xs, rb + 2 * dj + 1, 0, v.z, v.w);
        }
    }
    __syncthreads();

    // ---- Phases 1-3: MFMA layers (layer 1 xs->act; layers 2,3 in-place)
    mlp_layer<64, 128, false>(xs, WT1, b1, act, wave, lane);
    __syncthreads();
    mlp_layer<512, 1024, true>(act, WT2, b2, act, wave, lane);
    __syncthreads();
    mlp_layer<512, 1024, true>(act, WT3, b3, act, wave, lane);
    __syncthreads();

    // ---- Layer 4 (N=2, K=512) on VALU + sigmoid. 8 threads per output row.
    {
        const int row = tid >> 3, col = (tid >> 2) & 1, part = tid & 3;
        float s = 0.f;
        #pragma unroll
        for (int kk = 0; kk < 128; kk += 8) {
            const int k = part * 128 + kk;
            bf16x8 av = *reinterpret_cast<const bf16x8*>(
                act + (((unsigned)row * 1024u + (unsigned)k * 2u) ^ ((unsigned)(row & 7) << 4)));
            bf16x8 wv = *reinterpret_cast<const bf16x8*>(WT4 + col * 512 + k);
            #pragma unroll
            for (int jj = 0; jj < 8; ++jj) s += bf2f(av[jj]) * bf2f(wv[jj]);
        }
        s += __shfl_xor(s, 1, 64);
        s += __shfl_xor(s, 2, 64);
        if (part == 0) {
            const float z = s + b4[col];
            d1s[row][col] = 1.f / (1.f + expf(-z));
        }
    }
    __syncthreads();

    // ---- per-batch normalization over each batch's 32 users
    if (tid < 4) {
        const int bb = tid >> 1, cc = tid & 1;
        float s = 0.f;
        #pragma unroll
        for (int r = 0; r < NUSER; ++r) s += d1s[bb * 32 + r][cc];
        colsum[bb][cc] = s;
    }
    __syncthreads();
    if (tid < 128) {
        const int bb = tid >> 6, idx = tid & 63;
        out[(size_t)(b0 + bb) * 64 + idx] =
            Pp[0] * d1s[bb * 32 + (idx >> 1)][idx & 1] / colsum[bb][idx & 1];
    }
}

// ---------------------------------------------------------------------------
// Launch. d_in order: D, B, P_pow_normalized, D_0(unused), W1,b1, W2,b2, W3,b3, W4,b4
// ws layout: WT1(64 KB) | WT2(512 KB) | WT3(512 KB) | WT4(2 KB)  ~1.06 MB
// ---------------------------------------------------------------------------
extern "C" void kernel_launch(void* const* d_in, const int* in_sizes, int n_in,
                              void* d_out, int out_size, void* d_ws, size_t ws_size,
                              hipStream_t stream) {
    const float* D  = (const float*)d_in[0];
    const float* B  = (const float*)d_in[1];
    const float* Pp = (const float*)d_in[2];
    const float* W1 = (const float*)d_in[4];
    const float* b1 = (const float*)d_in[5];
    const float* W2 = (const float*)d_in[6];
    const float* b2 = (const float*)d_in[7];
    const float* W3 = (const float*)d_in[8];
    const float* b3 = (const float*)d_in[9];
    const float* W4 = (const float*)d_in[10];
    const float* b4 = (const float*)d_in[11];
    float* out = (float*)d_out;

    char* ws = (char*)d_ws;
    __hip_bfloat16* WT1 = (__hip_bfloat16*)(ws);
    __hip_bfloat16* WT2 = (__hip_bfloat16*)(ws + 65536);
    __hip_bfloat16* WT3 = (__hip_bfloat16*)(ws + 65536 + 524288);
    __hip_bfloat16* WT4 = (__hip_bfloat16*)(ws + 65536 + 524288 + 524288);

    transpose_cvt_all_kernel<<<144, 256, 0, stream>>>(W1, W2, W3, W4, WT1, WT2, WT3, WT4);

    fused_kernel<<<BATCH / 2, 512, 0, stream>>>(B, D, WT1, b1, WT2, b2, WT3, b3,
                                                WT4, b4, Pp, out);
}

// Round 10
// 396.966 us; speedup vs baseline: 1.0629x; 1.0010x over previous
//
#include <hip/hip_runtime.h>
#include <hip/hip_bf16.h>
#include <cstdint>
#include <cstddef>

// Problem constants
#define BATCH 512
#define NUSER 32
#define NM    64
#define FEATB 62
// rows through MLP = BATCH*NUSER = 16384, input width = 2 + 62 = 64
// One block = TWO batches (M=64 rows), 512 threads, 256 blocks (1 block/CU).
// R7 change: K-loop unroll 2 -> 4 in mlp_layer to hide ~200-cyc L2 latency
// of the per-ks 4x16B weight-fragment loads (tail is latency-bound at
// 2 waves/SIMD; MFMA per ks is only ~77 cyc vs ~200 cyc L2 hit).

#define SLICE_F4 (NM * NUSER * FEATB / 4)   // 31744 float4 per batch slice

typedef short bf16x8 __attribute__((ext_vector_type(8)));   // 8 bf16 (4 VGPRs) — MFMA A/B frag
typedef float f32x4  __attribute__((ext_vector_type(4)));   // MFMA C/D frag
typedef float f32x4v __attribute__((ext_vector_type(4)));   // ext-vector float4 (nontemporal-load eligible)

__device__ __forceinline__ float bf2f(short s) {
    union { unsigned int u; float f; } v;
    v.u = ((unsigned int)(unsigned short)s) << 16;
    return v.f;
}

// ---------------------------------------------------------------------------
// Kernel 1: ALL weight transposes in one launch.  W[K][N] f32 -> WT[N][K] bf16
// so MFMA B-fragments are contiguous-in-K 16B loads. 144 blocks, L2-resident.
// ---------------------------------------------------------------------------
__global__ void transpose_cvt_all_kernel(
        const float* __restrict__ W1, const float* __restrict__ W2,
        const float* __restrict__ W3, const float* __restrict__ W4,
        __hip_bfloat16* __restrict__ WT1, __hip_bfloat16* __restrict__ WT2,
        __hip_bfloat16* __restrict__ WT3, __hip_bfloat16* __restrict__ WT4) {
    __shared__ float t[64][65];          // +1 pad: conflict-free transposed reads
    const int idx = blockIdx.x;
    const float* W; __hip_bfloat16* WT; int K, N, kt, nt;
    if (idx < 8)        { W = W1; WT = WT1; K = 64;  N = 512; kt = 0;             nt = idx;          }
    else if (idx < 72)  { W = W2; WT = WT2; K = 512; N = 512; kt = (idx-8) >> 3;  nt = (idx-8) & 7;  }
    else if (idx < 136) { W = W3; WT = WT3; K = 512; N = 512; kt = (idx-72) >> 3; nt = (idx-72) & 7; }
    else                { W = W4; WT = WT4; K = 512; N = 2;   kt = idx - 136;     nt = 0;            }
    const int k0 = kt * 64, n0 = nt * 64;
    #pragma unroll
    for (int i = 0; i < 16; ++i) {
        int lin = threadIdx.x + i * 256;
        int r = lin >> 6, c = lin & 63;  // r: k-offset, c: n-offset (coalesced read)
        if (k0 + r < K && n0 + c < N) t[r][c] = W[(size_t)(k0 + r) * N + (n0 + c)];
    }
    __syncthreads();
    #pragma unroll
    for (int i = 0; i < 16; ++i) {
        int lin = threadIdx.x + i * 256;
        int r = lin >> 6, c = lin & 63;  // r: n-offset, c: k-offset (coalesced write)
        if (n0 + r < N && k0 + c < K)
            WT[(size_t)(n0 + r) * K + (k0 + c)] = __float2bfloat16(t[c][r]);
    }
}

// ---------------------------------------------------------------------------
// LDS helpers: X tile [64 rows][64 bf16 cols], 128 B rows, XOR-swizzled
// (G4: ^((row&7)<<4) balances all 32 banks for the MFMA A-reads).
// ---------------------------------------------------------------------------
__device__ __forceinline__ void xs_store_pair(char* xs, int row, int col, float a, float b) {
    __hip_bfloat162 h;
    h.x = __float2bfloat16(a); h.y = __float2bfloat16(b);
    *reinterpret_cast<__hip_bfloat162*>(
        xs + (((unsigned)row * 128u + (unsigned)col * 2u) ^ ((unsigned)(row & 7) << 4))) = h;
}
// jj indexes a float4 within one batch's [32][62] B_norm grid; rowbase = 0 or 32.
__device__ __forceinline__ void xs_store4(char* xs, int rowbase, int jj,
                                          float s0, float s1, float s2, float s3) {
    const int e = 4 * jj;
    const int user = rowbase + e / FEATB, feat = e % FEATB;   // feat is even
    xs_store_pair(xs, user, 2 + feat, s0, s1);
    if (feat == 60) xs_store_pair(xs, user + 1, 2, s2, s3);   // crosses user boundary
    else            xs_store_pair(xs, user, 4 + feat, s2, s3);
}

// ---------------------------------------------------------------------------
// One MLP layer: A (64 x K) from swizzled LDS, W^T (512 x K) bf16 from L2,
// 16x16x32 bf16 MFMA (validated absmax 3.7e-4), bias+ReLU epilogue to LDS.
// 8 waves; wave w owns cols [w*64, w*64+64). INPLACE: out_lds == a_lds is
// safe via the mid-barrier (all reads of a_lds complete before any store).
// R7: unroll 4 — 16 global + 16 LDS loads in flight to cover L2 latency.
// ---------------------------------------------------------------------------
template<int K, int ASTRIDE, bool INPLACE>
__device__ __forceinline__ void mlp_layer(const char* a_lds,
                                          const __hip_bfloat16* __restrict__ wt,  // [512][K]
                                          const float* __restrict__ bias,
                                          char* out_lds,                          // [64][512] bf16, swizzled
                                          int wave, int lane) {
    f32x4 acc[4][4] = {};
    const int colbase = wave * 64;
    const int lrow = lane & 15;
    const int kg   = (lane >> 4) * 8;
    const unsigned int sw = (unsigned int)(lrow & 7) << 4;  // (16m+lrow)&7 == lrow&7

    #pragma unroll 4
    for (int ks = 0; ks < K / 32; ++ks) {
        const int k0 = ks * 32 + kg;
        bf16x8 a[4];
        #pragma unroll
        for (int m = 0; m < 4; ++m)
            a[m] = *reinterpret_cast<const bf16x8*>(
                a_lds + ((((unsigned)(m * 16 + lrow) * ASTRIDE + k0 * 2)) ^ sw));
        bf16x8 bfrag[4];
        #pragma unroll
        for (int n = 0; n < 4; ++n) {
            const int col = colbase + n * 16 + lrow;
            bfrag[n] = *reinterpret_cast<const bf16x8*>(wt + (size_t)col * K + k0);
        }
        #pragma unroll
        for (int n = 0; n < 4; ++n)
            #pragma unroll
            for (int m = 0; m < 4; ++m)
                acc[m][n] = __builtin_amdgcn_mfma_f32_16x16x32_bf16(a[m], bfrag[n], acc[m][n], 0, 0, 0);
    }

    if (INPLACE) __syncthreads();   // drain ALL waves' reads before overwriting

    // epilogue: +bias, ReLU, bf16, swizzled LDS store
    // C/D layout (m89-verified): col = lane&15, row = (lane>>4)*4 + reg
    const int rg = (lane >> 4) * 4;
    #pragma unroll
    for (int m = 0; m < 4; ++m) {
        #pragma unroll
        for (int n = 0; n < 4; ++n) {
            const int col = colbase + n * 16 + lrow;
            const float bv = bias[col];
            #pragma unroll
            for (int r = 0; r < 4; ++r) {
                const int row = m * 16 + rg + r;
                float v = acc[m][n][r] + bv;
                v = fmaxf(v, 0.f);
                *reinterpret_cast<__hip_bfloat16*>(
                    out_lds + (((unsigned)row * 1024u + (unsigned)col * 2u) ^ ((unsigned)(row & 7) << 4)))
                    = __float2bfloat16(v);
            }
        }
    }
}

// ---------------------------------------------------------------------------
// Kernel 2 (mega): per block: TWO batches. B-reduce -> concat -> 4-layer MLP
// -> sigmoid -> per-batch normalize. 512 threads (8 waves), 256 blocks.
// LDS ~74 KB; single in-place act buffer. 1 block/CU; the MFMA tail is the
// only addressable cost above the ~41 us streaming floor.
// ---------------------------------------------------------------------------
__global__ __launch_bounds__(512, 2) void fused_kernel(
    const float* __restrict__ B, const float* __restrict__ D,
    const __hip_bfloat16* __restrict__ WT1, const float* __restrict__ b1,
    const __hip_bfloat16* __restrict__ WT2, const float* __restrict__ b2,
    const __hip_bfloat16* __restrict__ WT3, const float* __restrict__ b3,
    const __hip_bfloat16* __restrict__ WT4, const float* __restrict__ b4,
    const float* __restrict__ Pp, float* __restrict__ out) {

    __shared__ __align__(16) char xs[64 * 64 * 2];           // 8 KB  (X tile, 2 batches)
    __shared__ __align__(16) char act[64 * 512 * 2];         // 64 KB (in-place act)
    __shared__ float d1s[64][2];
    __shared__ float colsum[2][2];

    const int b0 = blockIdx.x * 2;       // this block's two batches: b0, b0+1
    const int tid = threadIdx.x;
    const int wave = tid >> 6, lane = tid & 63;

    // ---- Phase 0: B_norm = sum_m B[b,m,:,:] for b0 and b0+1 (1.02 MB stream)
    // Job space (float4): [0,496) b0-B | [496,992) b1-B | 16 D-b0 | 16 D-b1.
    // Thread t owns jobs t and t+512. Uniform m-loop, 2 nontemporal streams.
    {
        const f32x4v* p = reinterpret_cast<const f32x4v*>(B) + (size_t)b0 * SLICE_F4;
        const bool s0_b1 = (tid >= 496);                  // stream0: which batch
        const int  jj0   = s0_b1 ? tid - 496 : tid;
        const bool has1  = (tid < 480);                   // stream1 is a B-job
        const int  jj1   = tid + 16;                      // (only valid if has1)
        const f32x4v* p0 = p + (s0_b1 ? SLICE_F4 : 0) + jj0;
        const f32x4v* p1 = p + SLICE_F4 + jj1;
        f32x4v s0 = {0.f, 0.f, 0.f, 0.f};
        f32x4v s1 = {0.f, 0.f, 0.f, 0.f};
        #pragma unroll 8
        for (int m = 0; m < NM; ++m) {
            s0 += __builtin_nontemporal_load(p0 + (size_t)m * 496);
            if (has1)
                s1 += __builtin_nontemporal_load(p1 + (size_t)m * 496);
        }
        xs_store4(xs, s0_b1 ? 32 : 0, jj0, s0.x, s0.y, s0.z, s0.w);
        if (has1) {
            xs_store4(xs, 32, jj1, s1.x, s1.y, s1.z, s1.w);
        } else {
            // 32 threads handle the D concat: 16 float4 per batch (64 floats)
            const bool db1 = (tid >= 496);
            const int  dj  = db1 ? tid - 496 : tid - 480;
            const int  rb  = db1 ? 32 : 0;
            float4 v = reinterpret_cast<const float4*>(
                           D + (size_t)(b0 + (db1 ? 1 : 0)) * NUSER * 2)[dj];
            xs_store_pair(xs, rb + 2 * dj,     0, v.x, v.y);
            xs_store_pair(xs, rb + 2 * dj + 1, 0, v.z, v.w);
        }
    }
    __syncthreads();

    // ---- Phases 1-3: MFMA layers (layer 1 xs->act; layers 2,3 in-place)
    mlp_layer<64, 128, false>(xs, WT1, b1, act, wave, lane);
    __syncthreads();
    mlp_layer<512, 1024, true>(act, WT2, b2, act, wave, lane);
    __syncthreads();
    mlp_layer<512, 1024, true>(act, WT3, b3, act, wave, lane);
    __syncthreads();

    // ---- Layer 4 (N=2, K=512) on VALU + sigmoid. 8 threads per output row.
    {
        const int row = tid >> 3, col = (tid >> 2) & 1, part = tid & 3;
        float s = 0.f;
        #pragma unroll
        for (int kk = 0; kk < 128; kk += 8) {
            const int k = part * 128 + kk;
            bf16x8 av = *reinterpret_cast<const bf16x8*>(
                act + (((unsigned)row * 1024u + (unsigned)k * 2u) ^ ((unsigned)(row & 7) << 4)));
            bf16x8 wv = *reinterpret_cast<const bf16x8*>(WT4 + col * 512 + k);
            #pragma unroll
            for (int jj = 0; jj < 8; ++jj) s += bf2f(av[jj]) * bf2f(wv[jj]);
        }
        s += __shfl_xor(s, 1, 64);
        s += __shfl_xor(s, 2, 64);
        if (part == 0) {
            const float z = s + b4[col];
            d1s[row][col] = 1.f / (1.f + expf(-z));
        }
    }
    __syncthreads();

    // ---- per-batch normalization over each batch's 32 users
    if (tid < 4) {
        const int bb = tid >> 1, cc = tid & 1;
        float s = 0.f;
        #pragma unroll
        for (int r = 0; r < NUSER; ++r) s += d1s[bb * 32 + r][cc];
        colsum[bb][cc] = s;
    }
    __syncthreads();
    if (tid < 128) {
        const int bb = tid >> 6, idx = tid & 63;
        out[(size_t)(b0 + bb) * 64 + idx] =
            Pp[0] * d1s[bb * 32 + (idx >> 1)][idx & 1] / colsum[bb][idx & 1];
    }
}

// ---------------------------------------------------------------------------
// Launch. d_in order: D, B, P_pow_normalized, D_0(unused), W1,b1, W2,b2, W3,b3, W4,b4
// ws layout: WT1(64 KB) | WT2(512 KB) | WT3(512 KB) | WT4(2 KB)  ~1.06 MB
// ---------------------------------------------------------------------------
extern "C" void kernel_launch(void* const* d_in, const int* in_sizes, int n_in,
                              void* d_out, int out_size, void* d_ws, size_t ws_size,
                              hipStream_t stream) {
    const float* D  = (const float*)d_in[0];
    const float* B  = (const float*)d_in[1];
    const float* Pp = (const float*)d_in[2];
    const float* W1 = (const float*)d_in[4];
    const float* b1 = (const float*)d_in[5];
    const float* W2 = (const float*)d_in[6];
    const float* b2 = (const float*)d_in[7];
    const float* W3 = (const float*)d_in[8];
    const float* b3 = (const float*)d_in[9];
    const float* W4 = (const float*)d_in[10];
    const float* b4 = (const float*)d_in[11];
    float* out = (float*)d_out;

    char* ws = (char*)d_ws;
    __hip_bfloat16* WT1 = (__hip_bfloat16*)(ws);
    __hip_bfloat16* WT2 = (__hip_bfloat16*)(ws + 65536);
    __hip_bfloat16* WT3 = (__hip_bfloat16*)(ws + 65536 + 524288);
    __hip_bfloat16* WT4 = (__hip_bfloat16*)(ws + 65536 + 524288 + 524288);

    transpose_cvt_all_kernel<<<144, 256, 0, stream>>>(W1, W2, W3, W4, WT1, WT2, WT3, WT4);

    fused_kernel<<<BATCH / 2, 512, 0, stream>>>(B, D, WT1, b1, WT2, b2, WT3, b3,
                                                WT4, b4, Pp, out);
}